// Round 1
// baseline (1884.863 us; speedup 1.0000x reference)
//
#include <hip/hip_runtime.h>
#include <hip/hip_bf16.h>
#include <cstdint>

#define B_   32
#define LQ_  2048
#define LK_  2048
#define D_   256
#define INV_T 0.0625f   // 1/16

typedef __attribute__((ext_vector_type(8))) short bf16x8;
typedef __attribute__((ext_vector_type(4))) float f32x4;

// fp32 -> bf16 round-to-nearest-even (bit trick)
__device__ __forceinline__ unsigned short f2bf(float f) {
    union { float f; unsigned u; } a; a.f = f;
    unsigned u = a.u;
    unsigned r = (u + 0x7FFFu + ((u >> 16) & 1u)) >> 16;
    return (unsigned short)r;
}

// ---------------------------------------------------------------------------
// Kernel 1: P = mel ? 0 : exp((Q K^T)/16)  (unnormalized), rowsum += P
// Tile: 128x128 per block, 256 threads = 4 waves (2x2), wave does 64x64.
// bf16 MFMA 16x16x32, fp32 accum.
// ---------------------------------------------------------------------------
__global__ __launch_bounds__(256) void qk_exp_kernel(
    const float* __restrict__ q, const float* __restrict__ kmat,
    const int* __restrict__ mel, float* __restrict__ attn,
    float* __restrict__ rowsum)
{
    const int b  = blockIdx.z;
    const int m0 = blockIdx.y * 128;
    const int n0 = blockIdx.x * 128;

    __shared__ unsigned short As[128][72];   // q tile, bf16, pad to 72 (144B rows, 16B aligned)
    __shared__ unsigned short Bs[128][72];   // k tile, bf16

    const int tid  = threadIdx.x;
    const int wave = tid >> 6, lane = tid & 63;
    const int wm   = wave >> 1, wn = wave & 1;
    const int quad = lane >> 4, l16 = lane & 15;

    f32x4 acc[4][4];
#pragma unroll
    for (int i = 0; i < 4; ++i)
#pragma unroll
        for (int j = 0; j < 4; ++j) acc[i][j] = (f32x4)(0.0f);

    const float* qb = q    + (size_t)b * LQ_ * D_;
    const float* kb = kmat + (size_t)b * LK_ * D_;

    const int sr = tid >> 4;         // 0..15
    const int sc = (tid & 15) * 4;   // 0..60

    for (int kt = 0; kt < 4; ++kt) {
        const int kbase = kt * 64;
#pragma unroll
        for (int p = 0; p < 8; ++p) {
            const int row = sr + p * 16;
            float4 va = *(const float4*)&qb[(size_t)(m0 + row) * D_ + kbase + sc];
            float4 vb = *(const float4*)&kb[(size_t)(n0 + row) * D_ + kbase + sc];
            As[row][sc+0] = f2bf(va.x); As[row][sc+1] = f2bf(va.y);
            As[row][sc+2] = f2bf(va.z); As[row][sc+3] = f2bf(va.w);
            Bs[row][sc+0] = f2bf(vb.x); Bs[row][sc+1] = f2bf(vb.y);
            Bs[row][sc+2] = f2bf(vb.z); Bs[row][sc+3] = f2bf(vb.w);
        }
        __syncthreads();
#pragma unroll
        for (int ks = 0; ks < 2; ++ks) {
            bf16x8 af[4], bfr[4];
#pragma unroll
            for (int i = 0; i < 4; ++i)
                af[i] = *(const bf16x8*)&As[wm*64 + i*16 + l16][ks*32 + quad*8];
#pragma unroll
            for (int j = 0; j < 4; ++j)
                bfr[j] = *(const bf16x8*)&Bs[wn*64 + j*16 + l16][ks*32 + quad*8];
#pragma unroll
            for (int i = 0; i < 4; ++i)
#pragma unroll
                for (int j = 0; j < 4; ++j)
                    acc[i][j] = __builtin_amdgcn_mfma_f32_16x16x32_bf16(
                        af[i], bfr[j], acc[i][j], 0, 0, 0);
        }
        __syncthreads();
    }

    // Epilogue: P = mel ? 0 : exp(s/16); write; accumulate row sums.
    float*      attnB = attn + (size_t)b * LQ_ * LK_;
    const int*  melB  = mel  + (size_t)b * LQ_ * LK_;

    float rs[4][4];
#pragma unroll
    for (int i = 0; i < 4; ++i)
#pragma unroll
        for (int r = 0; r < 4; ++r) rs[i][r] = 0.0f;

#pragma unroll
    for (int i = 0; i < 4; ++i) {
#pragma unroll
        for (int j = 0; j < 4; ++j) {
#pragma unroll
            for (int r = 0; r < 4; ++r) {
                const int row = wm*64 + i*16 + quad*4 + r;  // C/D: row = quad*4+reg
                const int col = wn*64 + j*16 + l16;         // C/D: col = lane&15
                const size_t gi = (size_t)(m0 + row) * LK_ + (n0 + col);
                float s = acc[i][j][r] * INV_T;
                float p = melB[gi] ? 0.0f : __expf(s);
                attnB[gi] = p;
                rs[i][r] += p;
            }
        }
    }

#pragma unroll
    for (int i = 0; i < 4; ++i) {
#pragma unroll
        for (int r = 0; r < 4; ++r) {
            float s = rs[i][r];
            s += __shfl_xor(s, 1);
            s += __shfl_xor(s, 2);
            s += __shfl_xor(s, 4);
            s += __shfl_xor(s, 8);
            if (l16 == 0) {
                const int row = wm*64 + i*16 + quad*4 + r;
                atomicAdd(&rowsum[(size_t)b * LQ_ + m0 + row], s);
            }
        }
    }
}

// ---------------------------------------------------------------------------
// Kernel 2: a = src ? 0 : P/l; attn <- a (in place); O = a @ V
// Block: 64 q-rows x full D=256, 256 threads = 4 waves, wave does 64x64.
// Streams LK in tiles of 64. V transposed into LDS (K-contiguous) for B-frags.
// ---------------------------------------------------------------------------
__global__ __launch_bounds__(256) void pv_norm_kernel(
    const float* __restrict__ v, const int* __restrict__ src,
    const float* __restrict__ rowsum, float* __restrict__ attn,
    float* __restrict__ out)
{
    const int b  = blockIdx.y;
    const int m0 = blockIdx.x * 64;

    __shared__ unsigned short As[64][72];    // a tile, bf16 [m][k]
    __shared__ unsigned short Vt[256][72];   // V^T tile, bf16 [n][k]
    __shared__ float invl[64];

    const int tid  = threadIdx.x;
    const int wave = tid >> 6, lane = tid & 63;
    const int wn   = wave;                  // 4 waves cover D in 64-col strips
    const int quad = lane >> 4, l16 = lane & 15;

    if (tid < 64) invl[tid] = 1.0f / rowsum[(size_t)b * LQ_ + m0 + tid];
    __syncthreads();

    f32x4 acc[4][4];
#pragma unroll
    for (int i = 0; i < 4; ++i)
#pragma unroll
        for (int j = 0; j < 4; ++j) acc[i][j] = (f32x4)(0.0f);

    const float* vb    = v    + (size_t)b * LK_ * D_;
    float*       attnB = attn + (size_t)b * LQ_ * LK_;
    const int*   srcB  = src  + (size_t)b * LQ_ * LK_;

    const int sr = tid >> 4;         // 0..15
    const int sc = (tid & 15) * 4;   // 0..60

    for (int kt = 0; kt < 32; ++kt) {
        const int k0 = kt * 64;

        // Stage a-tile (64x64): read P, normalize, mask, write back, bf16 to LDS
#pragma unroll
        for (int p = 0; p < 4; ++p) {
            const int row = sr + p * 16;
            const size_t gi = (size_t)(m0 + row) * LK_ + k0 + sc;
            float4 pv = *(const float4*)&attnB[gi];
            int4   sv = *(const int4*)&srcB[gi];
            const float il = invl[row];
            float a0 = sv.x ? 0.0f : pv.x * il;
            float a1 = sv.y ? 0.0f : pv.y * il;
            float a2 = sv.z ? 0.0f : pv.z * il;
            float a3 = sv.w ? 0.0f : pv.w * il;
            float4 st; st.x = a0; st.y = a1; st.z = a2; st.w = a3;
            *(float4*)&attnB[gi] = st;
            As[row][sc+0] = f2bf(a0); As[row][sc+1] = f2bf(a1);
            As[row][sc+2] = f2bf(a2); As[row][sc+3] = f2bf(a3);
        }

        // Stage V^T tile (64 k-rows x 256 d-cols) via 4x4 register transpose
#pragma unroll
        for (int p = 0; p < 4; ++p) {
            const int bi  = tid + p * 256;
            const int bkv = (bi >> 6) * 4;   // 0..60
            const int bn  = (bi & 63) * 4;   // 0..252
            const float* s0 = &vb[(size_t)(k0 + bkv) * D_ + bn];
            float4 r0 = *(const float4*)(s0);
            float4 r1 = *(const float4*)(s0 + D_);
            float4 r2 = *(const float4*)(s0 + 2 * D_);
            float4 r3 = *(const float4*)(s0 + 3 * D_);
            unsigned short* d0 = &Vt[bn+0][bkv];
            d0[0]=f2bf(r0.x); d0[1]=f2bf(r1.x); d0[2]=f2bf(r2.x); d0[3]=f2bf(r3.x);
            unsigned short* d1 = &Vt[bn+1][bkv];
            d1[0]=f2bf(r0.y); d1[1]=f2bf(r1.y); d1[2]=f2bf(r2.y); d1[3]=f2bf(r3.y);
            unsigned short* d2 = &Vt[bn+2][bkv];
            d2[0]=f2bf(r0.z); d2[1]=f2bf(r1.z); d2[2]=f2bf(r2.z); d2[3]=f2bf(r3.z);
            unsigned short* d3 = &Vt[bn+3][bkv];
            d3[0]=f2bf(r0.w); d3[1]=f2bf(r1.w); d3[2]=f2bf(r2.w); d3[3]=f2bf(r3.w);
        }
        __syncthreads();

#pragma unroll
        for (int ks = 0; ks < 2; ++ks) {
            bf16x8 af[4], bfr[4];
#pragma unroll
            for (int i = 0; i < 4; ++i)
                af[i] = *(const bf16x8*)&As[i*16 + l16][ks*32 + quad*8];
#pragma unroll
            for (int j = 0; j < 4; ++j)
                bfr[j] = *(const bf16x8*)&Vt[wn*64 + j*16 + l16][ks*32 + quad*8];
#pragma unroll
            for (int i = 0; i < 4; ++i)
#pragma unroll
                for (int j = 0; j < 4; ++j)
                    acc[i][j] = __builtin_amdgcn_mfma_f32_16x16x32_bf16(
                        af[i], bfr[j], acc[i][j], 0, 0, 0);
        }
        __syncthreads();
    }

    // Epilogue: O tile 64 x 256
    float* outB = out + (size_t)b * LQ_ * D_;
#pragma unroll
    for (int i = 0; i < 4; ++i) {
#pragma unroll
        for (int j = 0; j < 4; ++j) {
#pragma unroll
            for (int r = 0; r < 4; ++r) {
                const int row = i*16 + quad*4 + r;
                const int col = wn*64 + j*16 + l16;
                outB[(size_t)(m0 + row) * D_ + col] = acc[i][j][r];
            }
        }
    }
}

extern "C" void kernel_launch(void* const* d_in, const int* in_sizes, int n_in,
                              void* d_out, int out_size, void* d_ws, size_t ws_size,
                              hipStream_t stream) {
    const float* q        = (const float*)d_in[0];
    const float* k        = (const float*)d_in[1];
    const float* v        = (const float*)d_in[2];
    const int*   src_mask = (const int*)d_in[3];
    const int*   mel_mask = (const int*)d_in[4];

    float* out  = (float*)d_out;                       // [B, LQ, D]
    float* attn = out + (size_t)B_ * LQ_ * D_;         // [B, LQ, LK]
    float* rowsum = (float*)d_ws;                      // [B, LQ]

    hipMemsetAsync(rowsum, 0, (size_t)B_ * LQ_ * sizeof(float), stream);

    qk_exp_kernel<<<dim3(LK_/128, LQ_/128, B_), 256, 0, stream>>>(
        q, k, mel_mask, attn, rowsum);

    pv_norm_kernel<<<dim3(LQ_/64, B_), 256, 0, stream>>>(
        v, src_mask, rowsum, attn, out);
}